// Round 4
// baseline (297.550 us; speedup 1.0000x reference)
//
#include <hip/hip_runtime.h>
#include <math.h>

#define B_ 16
#define P_ 19248
#define C_ 81
#define O_ 32
#define POS_TH 0.5f
#define NEG_TH 0.4f
#define RPB 128            // rows per k_main block; B_*P_ = 307968 = 2406*128
#define TPB 512            // threads per k_main block (8 waves), 4 threads/row
#define HBINS 1024         // top-level bins: fb>>21 (sign=0 since loss_c>=0)
#define CHUNK 2406         // P_/8 elements per (blockIdx.x) slice
#define SENT  0x7FFFFFFF

__device__ __forceinline__ float sl1(float x) {
    float d = fabsf(x);
    return (d < 1.0f) ? 0.5f * d * d : d - 0.5f;
}

__device__ __forceinline__ float iou_gt_prior(float4 t, float4 pr) {
    float px1 = pr.x - pr.z * 0.5f;
    float py1 = pr.y - pr.w * 0.5f;
    float px2 = pr.x + pr.z * 0.5f;
    float py2 = pr.y + pr.w * 0.5f;
    float ltx = fmaxf(t.x, px1), lty = fmaxf(t.y, py1);
    float rbx = fminf(t.z, px2), rby = fminf(t.w, py2);
    float iw = fmaxf(rbx - ltx, 0.0f), ih = fmaxf(rby - lty, 0.0f);
    float inter = iw * ih;
    float area_t = (t.z - t.x) * (t.w - t.y);
    float area_p = (px2 - px1) * (py2 - py1);
    return inter / (area_t + area_p - inter);
}

__global__ void k_init(int* __restrict__ hist, int* __restrict__ num_pos,
                       int* __restrict__ cand_cnt, float* __restrict__ ce_part,
                       float* __restrict__ accum) {
    int t = blockIdx.x * blockDim.x + threadIdx.x;
    for (int i = t; i < B_ * HBINS; i += gridDim.x * blockDim.x) hist[i] = 0;
    if (t < B_) { num_pos[t] = 0; cand_cnt[t] = 0; ce_part[t] = 0.0f; }
    if (t < 2) accum[t] = 0.0f;
}

// One block per (b,o): argmax over P priors (first occurrence on ties).
__global__ void k_best_prior(const float* __restrict__ priors,
                             const float* __restrict__ gt_boxes,
                             int* __restrict__ best_pr) {
    int b = blockIdx.x / O_;
    int o = blockIdx.x % O_;
    float4 t = ((const float4*)gt_boxes)[b * O_ + o];
    float bestv = -1.0f; int besti = 0;
    for (int p = threadIdx.x; p < P_; p += blockDim.x) {
        float4 pr = ((const float4*)priors)[p];
        float v = iou_gt_prior(t, pr);
        if (v > bestv) { bestv = v; besti = p; }
    }
    __shared__ float sv[256];
    __shared__ int   si[256];
    sv[threadIdx.x] = bestv; si[threadIdx.x] = besti;
    __syncthreads();
    for (int s = 128; s > 0; s >>= 1) {
        if (threadIdx.x < s) {
            float ov = sv[threadIdx.x + s]; int oi = si[threadIdx.x + s];
            if (ov > sv[threadIdx.x] ||
                (ov == sv[threadIdx.x] && oi < si[threadIdx.x])) {
                sv[threadIdx.x] = ov; si[threadIdx.x] = oi;
            }
        }
        __syncthreads();
    }
    if (threadIdx.x == 0) best_pr[b * O_ + o] = si[0];
}

// One thread per (b,p): max/argmax over O gts (first occurrence on ties).
__global__ void k_best_truth(const float* __restrict__ priors,
                             const float* __restrict__ gt_boxes,
                             float* __restrict__ bt_ov,
                             int* __restrict__ bt_ix) {
    int b = blockIdx.y;
    int p = blockIdx.x * blockDim.x + threadIdx.x;
    __shared__ float4 gt[O_];
    if (threadIdx.x < O_) gt[threadIdx.x] = ((const float4*)gt_boxes)[b * O_ + threadIdx.x];
    __syncthreads();
    if (p >= P_) return;
    float4 pr = ((const float4*)priors)[p];
    float bestv = -1.0f; int besti = 0;
    for (int o = 0; o < O_; ++o) {
        float v = iou_gt_prior(gt[o], pr);
        if (v > bestv) { bestv = v; besti = o; }
    }
    size_t bp = (size_t)b * P_ + p;
    bt_ov[bp] = bestv;
    bt_ix[bp] = besti;
}

// Force-match: sequential per batch (numpy last-wins scatter semantics).
__global__ void k_force(const int* __restrict__ best_pr,
                        float* __restrict__ bt_ov,
                        int* __restrict__ bt_ix) {
    int b = threadIdx.x;
    if (b >= B_) return;
    for (int o = 0; o < O_; ++o) {
        int p = best_pr[b * O_ + o];
        size_t bp = (size_t)b * P_ + p;
        bt_ov[bp] = 2.0f;
        bt_ix[bp] = o;
    }
}

// Main pass: 512 threads stage 128 rows (41.5KB) via coalesced float4, then
// 4 threads/row reduce (logsumexp) with two shfl_xor combines.
__global__ __launch_bounds__(TPB, 6) void
k_main(const float* __restrict__ loc_data,
       const float* __restrict__ conf_data,
       const float* __restrict__ priors,
       const float* __restrict__ gt_boxes,
       const int* __restrict__ gt_labels,
       const float* __restrict__ bt_ov,
       const int* __restrict__ bt_ix,
       float* __restrict__ lossc,
       float* __restrict__ ce_neg,
       int* __restrict__ num_pos,
       float* __restrict__ accum) {
    __shared__ float srow[RPB * C_];          // 41472 B
    __shared__ float s_lB, s_ceP;
    __shared__ int s_np;
    const int row0 = blockIdx.x * RPB;
    const int tid = threadIdx.x;
    if (tid == 0) { s_lB = 0.0f; s_ceP = 0.0f; s_np = 0; }

    {
        const float4* src = (const float4*)(conf_data + (size_t)row0 * C_);
        float4* dst = (float4*)srow;
        float4 t0 = src[tid];
        float4 t1 = src[tid + 512];
        float4 t2 = src[tid + 1024];
        float4 t3 = src[tid + 1536];
        float4 t4 = src[tid + 2048];
        float4 t5;
        if (tid < 32) t5 = src[tid + 2560];
        dst[tid]        = t0;
        dst[tid + 512]  = t1;
        dst[tid + 1024] = t2;
        dst[tid + 1536] = t3;
        dst[tid + 2048] = t4;
        if (tid < 32) dst[tid + 2560] = t5;
    }
    __syncthreads();

    const int r = tid >> 2;
    const int q = tid & 3;
    const int bp = row0 + r;
    const int b = bp / P_;
    const int p = bp - b * P_;
    const float* row = srow + r * C_;
    const int j0 = 20 * q;

    float ma = row[j0], mb = row[j0 + 1], mc = row[j0 + 2], md = row[j0 + 3];
    #pragma unroll
    for (int i = 4; i < 20; i += 4) {
        ma = fmaxf(ma, row[j0 + i]);     mb = fmaxf(mb, row[j0 + i + 1]);
        mc = fmaxf(mc, row[j0 + i + 2]); md = fmaxf(md, row[j0 + i + 3]);
    }
    float m = fmaxf(fmaxf(ma, mb), fmaxf(mc, md));
    if (q == 3) m = fmaxf(m, row[80]);
    m = fmaxf(m, __shfl_xor(m, 1));
    m = fmaxf(m, __shfl_xor(m, 2));

    float sa = 0.f, sb = 0.f, sc = 0.f, sd = 0.f;
    #pragma unroll
    for (int i = 0; i < 20; i += 4) {
        sa += __expf(row[j0 + i] - m);     sb += __expf(row[j0 + i + 1] - m);
        sc += __expf(row[j0 + i + 2] - m); sd += __expf(row[j0 + i + 3] - m);
    }
    float s = (sa + sb) + (sc + sd);
    if (q == 3) s += __expf(row[80] - m);
    s += __shfl_xor(s, 1);
    s += __shfl_xor(s, 2);
    float logZ = m + __logf(s);

    if (q == 0) {
        float ov = bt_ov[bp];
        int ti = bt_ix[bp];
        int conf_t = gt_labels[b * O_ + ti] + 1;
        if (ov < POS_TH) conf_t = -1;
        if (ov < NEG_TH) conf_t = 0;
        bool pos = conf_t > 0;

        float conf0 = row[0];
        float lc = (pos || conf_t < 0) ? 0.0f : (logZ - conf0);
        int cls = pos ? conf_t : 0;
        float ce = logZ - row[cls];

        lossc[bp] = lc;
        ce_neg[bp] = (conf_t == 0) ? ce : 0.0f;

        if (pos) {
            float4 t = ((const float4*)gt_boxes)[b * O_ + ti];
            float4 pr = ((const float4*)priors)[p];
            float mcx = (t.x + t.z) * 0.5f;
            float mcy = (t.y + t.w) * 0.5f;
            float gx = (mcx - pr.x) / (0.1f * pr.z);
            float gy = (mcy - pr.y) / (0.1f * pr.w);
            float gw = logf((t.z - t.x) / pr.z) / 0.2f;
            float gh = logf((t.w - t.y) / pr.w) / 0.2f;
            float4 ld = ((const float4*)loc_data)[bp];
            float sc2 = sl1(ld.x - gx) + sl1(ld.y - gy) + sl1(ld.z - gw) + sl1(ld.w - gh);
            atomicAdd(&s_lB, sc2);
            atomicAdd(&s_ceP, ce);
            atomicAdd(&s_np, 1);
        }
    }
    __syncthreads();
    if (tid == 0 && s_np > 0) {
        atomicAdd(&accum[0], s_lB);
        atomicAdd(&accum[1], s_ceP);
        atomicAdd(&num_pos[b], s_np);
    }
}

// Stage 1: per-batch 1024-bin histogram of fb>>21 (monotone since lc>=0).
__global__ __launch_bounds__(512) void
k_hist(const float* __restrict__ lossc, int* __restrict__ hist) {
    __shared__ int h[HBINS];
    int b = blockIdx.y;
    const float* lc = lossc + (size_t)b * P_;
    for (int i = threadIdx.x; i < HBINS; i += 512) h[i] = 0;
    __syncthreads();
    int start = blockIdx.x * CHUNK;
    for (int i = start + threadIdx.x; i < start + CHUNK; i += 512)
        atomicAdd(&h[__float_as_uint(lc[i]) >> 21], 1);
    __syncthreads();
    int* gh = hist + b * HBINS;
    for (int i = threadIdx.x; i < HBINS; i += 512)
        if (h[i]) atomicAdd(&gh[i], h[i]);
}

// Stage 2: per batch, find threshold bin T (k-th largest lives in it) + residual kk.
__global__ void k_pick(const int* __restrict__ hist, const int* __restrict__ num_pos,
                       int* __restrict__ Tarr, int* __restrict__ kkarr) {
    int b = blockIdx.x;
    const int* gh = hist + b * HBINS;
    int k = 3 * num_pos[b];
    if (k > P_ - 1) k = P_ - 1;
    __shared__ int chunk[256];
    int s = 0;
    #pragma unroll
    for (int j = 0; j < 4; ++j) s += gh[threadIdx.x * 4 + j];
    chunk[threadIdx.x] = s;
    __syncthreads();
    if (threadIdx.x == 0) {
        if (k <= 0) { Tarr[b] = SENT; kkarr[b] = 0; }
        else {
            int cum = 0, c = 255;
            for (; c >= 0; --c) { if (cum + chunk[c] >= k) break; cum += chunk[c]; }
            int T = 0, kk = k - cum;
            for (int j = 3; j >= 0; --j) {
                int bin = c * 4 + j;
                int h = gh[bin];
                if (h >= kk) { T = bin; break; }
                kk -= h;
            }
            Tarr[b] = T; kkarr[b] = kk;
        }
    }
}

// Stage 3: sum ce over bins strictly above T (fully selected); collect bin==T
// candidates' indices.
__global__ __launch_bounds__(512) void
k_sumcand(const float* __restrict__ lossc, const float* __restrict__ ce_neg,
          const int* __restrict__ Tarr, int* __restrict__ cand,
          int* __restrict__ cand_cnt, float* __restrict__ ce_part) {
    int b = blockIdx.y;
    int T = Tarr[b];
    const float* lc = lossc + (size_t)b * P_;
    const float* cn = ce_neg + (size_t)b * P_;
    int start = blockIdx.x * CHUNK;
    float sum = 0.0f;
    for (int i = start + threadIdx.x; i < start + CHUNK; i += 512) {
        int bin = (int)(__float_as_uint(lc[i]) >> 21);
        if (bin > T) sum += cn[i];
        else if (bin == T) {
            int slot = atomicAdd(&cand_cnt[b], 1);
            cand[(size_t)b * P_ + slot] = i;
        }
    }
    __shared__ float red[512];
    red[threadIdx.x] = sum;
    __syncthreads();
    for (int s = 256; s > 0; s >>= 1) {
        if (threadIdx.x < s) red[threadIdx.x] += red[threadIdx.x + s];
        __syncthreads();
    }
    if (threadIdx.x == 0 && red[0] != 0.0f) atomicAdd(&ce_part[b], red[0]);
}

// Stage 4: exact select among bin-T candidates. Radix over remaining 21 value
// bits (11 + 10); on value ties straddling the boundary, tie-break by smallest
// index (radix over 15 index bits) — exactly matching stable argsort(-loss_c).
__global__ __launch_bounds__(512) void
k_finalsel(const float* __restrict__ lossc, const float* __restrict__ ce_neg,
           const int* __restrict__ cand, const int* __restrict__ cand_cnt,
           const int* __restrict__ Tarr, const int* __restrict__ kkarr,
           const float* __restrict__ ce_part, float* __restrict__ ce_sum) {
    int b = blockIdx.x;
    int n = cand_cnt[b];
    if (n == 0) {
        if (threadIdx.x == 0) ce_sum[b] = ce_part[b];
        return;
    }
    int kk = kkarr[b];
    const float* lc = lossc + (size_t)b * P_;
    const float* cn = ce_neg + (size_t)b * P_;
    const int* cd = cand + (size_t)b * P_;
    __shared__ int h[2048];
    __shared__ int s_d, s_kk;

    // round 1: bits 20..10
    for (int i = threadIdx.x; i < 2048; i += 512) h[i] = 0;
    __syncthreads();
    for (int i = threadIdx.x; i < n; i += 512)
        atomicAdd(&h[(__float_as_uint(lc[cd[i]]) >> 10) & 2047], 1);
    __syncthreads();
    if (threadIdx.x == 0) {
        int cum = 0, d = 2047;
        for (; d >= 0; --d) { if (cum + h[d] >= kk) break; cum += h[d]; }
        s_d = d; s_kk = kk - cum;
    }
    __syncthreads();
    unsigned int hi = (unsigned int)s_d;
    kk = s_kk;
    __syncthreads();

    // round 0: bits 9..0
    for (int i = threadIdx.x; i < 1024; i += 512) h[i] = 0;
    __syncthreads();
    for (int i = threadIdx.x; i < n; i += 512) {
        unsigned int fb = __float_as_uint(lc[cd[i]]);
        if (((fb >> 10) & 2047) == hi) atomicAdd(&h[fb & 1023], 1);
    }
    __syncthreads();
    if (threadIdx.x == 0) {
        int cum = 0, d = 1023;
        for (; d >= 0; --d) { if (cum + h[d] >= kk) break; cum += h[d]; }
        s_d = d; s_kk = kk - cum;
    }
    __syncthreads();
    unsigned int V = (((unsigned int)Tarr[b]) << 21) | (hi << 10) | (unsigned int)s_d;
    int ee = h[s_d];
    kk = s_kk;

    float sum = 0.0f;
    if (kk == ee) {
        // no boundary-straddling ties: take everything >= V
        for (int i = threadIdx.x; i < n; i += 512) {
            int idx = cd[i];
            if (__float_as_uint(lc[idx]) >= V) sum += cn[idx];
        }
    } else {
        // take kk smallest indices among fb == V (stable-sort order)
        __syncthreads();
        for (int i = threadIdx.x; i < 256; i += 512) h[i] = 0;
        __syncthreads();
        for (int i = threadIdx.x; i < n; i += 512) {
            int idx = cd[i];
            if (__float_as_uint(lc[idx]) == V) atomicAdd(&h[idx >> 7], 1);
        }
        __syncthreads();
        if (threadIdx.x == 0) {
            int cum = 0, d = 0;
            for (; d < 256; ++d) { if (cum + h[d] >= kk) break; cum += h[d]; }
            s_d = d; s_kk = kk - cum;
        }
        __syncthreads();
        int ihi = s_d;
        kk = s_kk;
        __syncthreads();
        for (int i = threadIdx.x; i < 128; i += 512) h[i] = 0;
        __syncthreads();
        for (int i = threadIdx.x; i < n; i += 512) {
            int idx = cd[i];
            if (__float_as_uint(lc[idx]) == V && (idx >> 7) == ihi)
                atomicAdd(&h[idx & 127], 1);
        }
        __syncthreads();
        if (threadIdx.x == 0) {
            int cum = 0, d = 0;
            for (; d < 128; ++d) { if (cum + h[d] >= kk) break; cum += h[d]; }
            s_d = d;
        }
        __syncthreads();
        int Istar = (ihi << 7) | s_d;
        for (int i = threadIdx.x; i < n; i += 512) {
            int idx = cd[i];
            unsigned int fb = __float_as_uint(lc[idx]);
            if (fb > V || (fb == V && idx <= Istar)) sum += cn[idx];
        }
    }
    __shared__ float red[512];
    red[threadIdx.x] = sum;
    __syncthreads();
    for (int s = 256; s > 0; s >>= 1) {
        if (threadIdx.x < s) red[threadIdx.x] += red[threadIdx.x + s];
        __syncthreads();
    }
    if (threadIdx.x == 0) ce_sum[b] = ce_part[b] + red[0];
}

__global__ void k_final(const int* __restrict__ num_pos,
                        const float* __restrict__ ce_sum,
                        const float* __restrict__ accum,
                        float* __restrict__ out) {
    if (threadIdx.x != 0) return;
    int tp = 0; float ns = 0.0f;
    for (int b = 0; b < B_; ++b) { tp += num_pos[b]; ns += ce_sum[b]; }
    float inv = 1.0f / (float)tp;
    out[0] = accum[0] * 1.5f * inv;          // BBOX_ALPHA
    out[1] = (accum[1] + ns) * 1.0f * inv;   // CONF_ALPHA
}

extern "C" void kernel_launch(void* const* d_in, const int* in_sizes, int n_in,
                              void* d_out, int out_size, void* d_ws, size_t ws_size,
                              hipStream_t stream) {
    const float* loc    = (const float*)d_in[0];
    const float* conf   = (const float*)d_in[1];
    const float* priors = (const float*)d_in[2];
    const float* gtb    = (const float*)d_in[3];
    const int*   gtl    = (const int*)d_in[4];
    float* out = (float*)d_out;

    const size_t BP = (size_t)B_ * P_;
    float* W = (float*)d_ws;
    float* bt_ov    = W;
    int*   bt_ix    = (int*)(W + BP);
    float* lossc    = W + 2 * BP;
    float* ce_neg   = W + 3 * BP;
    int*   cand     = (int*)(W + 4 * BP);
    int*   hist     = (int*)(W + 5 * BP);
    int*   best_pr  = hist + B_ * HBINS;
    int*   num_pos  = best_pr + B_ * O_;
    int*   cand_cnt = num_pos + B_;
    int*   Tarr     = cand_cnt + B_;
    int*   kkarr    = Tarr + B_;
    float* ce_part  = (float*)(kkarr + B_);
    float* ce_sum   = ce_part + B_;
    float* accum    = ce_sum + B_;

    hipLaunchKernelGGL(k_init, dim3(32), dim3(512), 0, stream,
                       hist, num_pos, cand_cnt, ce_part, accum);
    hipLaunchKernelGGL(k_best_prior, dim3(B_ * O_), dim3(256), 0, stream,
                       priors, gtb, best_pr);
    hipLaunchKernelGGL(k_best_truth, dim3((P_ + 255) / 256, B_), dim3(256), 0, stream,
                       priors, gtb, bt_ov, bt_ix);
    hipLaunchKernelGGL(k_force, dim3(1), dim3(64), 0, stream, best_pr, bt_ov, bt_ix);
    hipLaunchKernelGGL(k_main, dim3((int)(BP / RPB)), dim3(TPB), 0, stream,
                       loc, conf, priors, gtb, gtl, bt_ov, bt_ix,
                       lossc, ce_neg, num_pos, accum);
    hipLaunchKernelGGL(k_hist, dim3(8, B_), dim3(512), 0, stream, lossc, hist);
    hipLaunchKernelGGL(k_pick, dim3(B_), dim3(256), 0, stream,
                       hist, num_pos, Tarr, kkarr);
    hipLaunchKernelGGL(k_sumcand, dim3(8, B_), dim3(512), 0, stream,
                       lossc, ce_neg, Tarr, cand, cand_cnt, ce_part);
    hipLaunchKernelGGL(k_finalsel, dim3(B_), dim3(512), 0, stream,
                       lossc, ce_neg, cand, cand_cnt, Tarr, kkarr, ce_part, ce_sum);
    hipLaunchKernelGGL(k_final, dim3(1), dim3(64), 0, stream,
                       num_pos, ce_sum, accum, out);
}

// Round 6
// 164.843 us; speedup vs baseline: 1.8051x; 1.8051x over previous
//
#include <hip/hip_runtime.h>
#include <math.h>

#define B_ 16
#define P_ 19248
#define C_ 81
#define O_ 32
#define POS_TH 0.5f
#define NEG_TH 0.4f
#define RPB 128            // rows per k_main block; B_*P_ = 307968 = 2406*128
#define TPB 512            // threads per k_main block (8 waves), 4 threads/row
#define HBINS 1024         // top-level bins: fb>>21 (sign=0 since loss_c>=0)
#define CHUNK 2406         // P_/8 elements per k_hist slice

__device__ __forceinline__ float sl1(float x) {
    float d = fabsf(x);
    return (d < 1.0f) ? 0.5f * d * d : d - 0.5f;
}

__device__ __forceinline__ float iou_gt_prior(float4 t, float4 pr) {
    float px1 = pr.x - pr.z * 0.5f;
    float py1 = pr.y - pr.w * 0.5f;
    float px2 = pr.x + pr.z * 0.5f;
    float py2 = pr.y + pr.w * 0.5f;
    float ltx = fmaxf(t.x, px1), lty = fmaxf(t.y, py1);
    float rbx = fminf(t.z, px2), rby = fminf(t.w, py2);
    float iw = fmaxf(rbx - ltx, 0.0f), ih = fmaxf(rby - lty, 0.0f);
    float inter = iw * ih;
    float area_t = (t.z - t.x) * (t.w - t.y);
    float area_p = (px2 - px1) * (py2 - py1);
    return inter / (area_t + area_p - inter);
}

// ---- parallel threshold pick (512 threads, 8 waves) ----
// Find bin d such that the cumulative count FROM THE TOP crosses kk:
// sum_{j>d} h[j] < kk <= sum_{j>=d} h[j].  Writes d -> *s_bin, residual -> *s_kk.
template <int PER>
__device__ __forceinline__ void pick_top(const int* __restrict__ h, int kk, int tid,
                                         int* s_bin, int* s_kk, int* wsum) {
    const int lane = tid & 63, wid = tid >> 6;
    const int base = tid * PER;
    int v[PER]; int s = 0;
    #pragma unroll
    for (int j = 0; j < PER; ++j) { v[j] = h[base + j]; s += v[j]; }
    int x = s;                                  // inclusive suffix scan in wave
    #pragma unroll
    for (int d = 1; d < 64; d <<= 1) {
        int y = __shfl_down(x, d);
        if (lane + d < 64) x += y;
    }
    if (lane == 0) wsum[wid] = x;
    __syncthreads();
    int above = 0;
    #pragma unroll
    for (int w = 0; w < 8; ++w) if (w > wid) above += wsum[w];
    int T = (x - s) + above;                    // count in bins above my chunk
    if (T < kk && kk <= T + s) {                // exactly one thread true
        int kl = kk - T, cum = 0;
        #pragma unroll
        for (int j = PER - 1; j >= 0; --j) {
            if (cum + v[j] >= kl) { *s_bin = base + j; *s_kk = kl - cum; break; }
            cum += v[j];
        }
    }
    __syncthreads();
}

// Mirror: cumulative FROM THE BOTTOM (kk-th smallest bin).
template <int PER>
__device__ __forceinline__ void pick_bot(const int* __restrict__ h, int kk, int tid,
                                         int* s_bin, int* s_kk, int* wsum) {
    const int lane = tid & 63, wid = tid >> 6;
    const int base = tid * PER;
    int v[PER]; int s = 0;
    #pragma unroll
    for (int j = 0; j < PER; ++j) { v[j] = h[base + j]; s += v[j]; }
    int x = s;                                  // inclusive prefix scan in wave
    #pragma unroll
    for (int d = 1; d < 64; d <<= 1) {
        int y = __shfl_up(x, d);
        if (lane >= d) x += y;
    }
    if (lane == 63) wsum[wid] = x;
    __syncthreads();
    int below = 0;
    #pragma unroll
    for (int w = 0; w < 8; ++w) if (w < wid) below += wsum[w];
    int T = (x - s) + below;
    if (T < kk && kk <= T + s) {
        int kl = kk - T, cum = 0;
        #pragma unroll
        for (int j = 0; j < PER; ++j) {
            if (cum + v[j] >= kl) { *s_bin = base + j; *s_kk = kl - cum; break; }
            cum += v[j];
        }
    }
    __syncthreads();
}

__global__ void k_init(int* __restrict__ hist, int* __restrict__ num_pos,
                       float* __restrict__ accum) {
    int t = blockIdx.x * blockDim.x + threadIdx.x;
    if (t < B_ * HBINS) hist[t] = 0;
    if (t < B_) num_pos[t] = 0;
    if (t < 2) accum[t] = 0.0f;
}

// One block per (b,o): argmax over P priors (first occurrence on ties).
__global__ void k_best_prior(const float* __restrict__ priors,
                             const float* __restrict__ gt_boxes,
                             int* __restrict__ best_pr) {
    int b = blockIdx.x / O_;
    int o = blockIdx.x % O_;
    float4 t = ((const float4*)gt_boxes)[b * O_ + o];
    float bestv = -1.0f; int besti = 0;
    for (int p = threadIdx.x; p < P_; p += blockDim.x) {
        float4 pr = ((const float4*)priors)[p];
        float v = iou_gt_prior(t, pr);
        if (v > bestv) { bestv = v; besti = p; }
    }
    __shared__ float sv[256];
    __shared__ int   si[256];
    sv[threadIdx.x] = bestv; si[threadIdx.x] = besti;
    __syncthreads();
    for (int s = 128; s > 0; s >>= 1) {
        if (threadIdx.x < s) {
            float ov = sv[threadIdx.x + s]; int oi = si[threadIdx.x + s];
            if (ov > sv[threadIdx.x] ||
                (ov == sv[threadIdx.x] && oi < si[threadIdx.x])) {
                sv[threadIdx.x] = ov; si[threadIdx.x] = oi;
            }
        }
        __syncthreads();
    }
    if (threadIdx.x == 0) best_pr[b * O_ + o] = si[0];
}

// One thread per (b,p): max/argmax over O gts (first occurrence on ties).
__global__ void k_best_truth(const float* __restrict__ priors,
                             const float* __restrict__ gt_boxes,
                             float* __restrict__ bt_ov,
                             int* __restrict__ bt_ix) {
    int b = blockIdx.y;
    int p = blockIdx.x * blockDim.x + threadIdx.x;
    __shared__ float4 gt[O_];
    if (threadIdx.x < O_) gt[threadIdx.x] = ((const float4*)gt_boxes)[b * O_ + threadIdx.x];
    __syncthreads();
    if (p >= P_) return;
    float4 pr = ((const float4*)priors)[p];
    float bestv = -1.0f; int besti = 0;
    for (int o = 0; o < O_; ++o) {
        float v = iou_gt_prior(gt[o], pr);
        if (v > bestv) { bestv = v; besti = o; }
    }
    size_t bp = (size_t)b * P_ + p;
    bt_ov[bp] = bestv;
    bt_ix[bp] = besti;
}

// Force-match: sequential per batch (numpy last-wins scatter semantics).
__global__ void k_force(const int* __restrict__ best_pr,
                        float* __restrict__ bt_ov,
                        int* __restrict__ bt_ix) {
    int b = threadIdx.x;
    if (b >= B_) return;
    for (int o = 0; o < O_; ++o) {
        int p = best_pr[b * O_ + o];
        size_t bp = (size_t)b * P_ + p;
        bt_ov[bp] = 2.0f;
        bt_ix[bp] = o;
    }
}

// Main pass: 512 threads stage 128 rows (41.5KB) via coalesced float4, then
// 4 threads/row reduce (logsumexp) with two shfl_xor combines.
__global__ __launch_bounds__(TPB, 6) void
k_main(const float* __restrict__ loc_data,
       const float* __restrict__ conf_data,
       const float* __restrict__ priors,
       const float* __restrict__ gt_boxes,
       const int* __restrict__ gt_labels,
       const float* __restrict__ bt_ov,
       const int* __restrict__ bt_ix,
       float* __restrict__ lossc,
       float* __restrict__ ce_neg,
       int* __restrict__ num_pos,
       float* __restrict__ accum) {
    __shared__ float srow[RPB * C_];          // 41472 B
    __shared__ float s_lB, s_ceP;
    __shared__ int s_np;
    const int row0 = blockIdx.x * RPB;
    const int tid = threadIdx.x;
    if (tid == 0) { s_lB = 0.0f; s_ceP = 0.0f; s_np = 0; }

    {
        const float4* src = (const float4*)(conf_data + (size_t)row0 * C_);
        float4* dst = (float4*)srow;
        float4 t0 = src[tid];
        float4 t1 = src[tid + 512];
        float4 t2 = src[tid + 1024];
        float4 t3 = src[tid + 1536];
        float4 t4 = src[tid + 2048];
        float4 t5;
        if (tid < 32) t5 = src[tid + 2560];
        dst[tid]        = t0;
        dst[tid + 512]  = t1;
        dst[tid + 1024] = t2;
        dst[tid + 1536] = t3;
        dst[tid + 2048] = t4;
        if (tid < 32) dst[tid + 2560] = t5;
    }
    __syncthreads();

    const int r = tid >> 2;
    const int q = tid & 3;
    const int bp = row0 + r;
    const int b = bp / P_;
    const int p = bp - b * P_;
    const float* row = srow + r * C_;
    const int j0 = 20 * q;

    float ma = row[j0], mb = row[j0 + 1], mc = row[j0 + 2], md = row[j0 + 3];
    #pragma unroll
    for (int i = 4; i < 20; i += 4) {
        ma = fmaxf(ma, row[j0 + i]);     mb = fmaxf(mb, row[j0 + i + 1]);
        mc = fmaxf(mc, row[j0 + i + 2]); md = fmaxf(md, row[j0 + i + 3]);
    }
    float m = fmaxf(fmaxf(ma, mb), fmaxf(mc, md));
    if (q == 3) m = fmaxf(m, row[80]);
    m = fmaxf(m, __shfl_xor(m, 1));
    m = fmaxf(m, __shfl_xor(m, 2));

    float sa = 0.f, sb = 0.f, sc = 0.f, sd = 0.f;
    #pragma unroll
    for (int i = 0; i < 20; i += 4) {
        sa += __expf(row[j0 + i] - m);     sb += __expf(row[j0 + i + 1] - m);
        sc += __expf(row[j0 + i + 2] - m); sd += __expf(row[j0 + i + 3] - m);
    }
    float s = (sa + sb) + (sc + sd);
    if (q == 3) s += __expf(row[80] - m);
    s += __shfl_xor(s, 1);
    s += __shfl_xor(s, 2);
    float logZ = m + __logf(s);

    if (q == 0) {
        float ov = bt_ov[bp];
        int ti = bt_ix[bp];
        int conf_t = gt_labels[b * O_ + ti] + 1;
        if (ov < POS_TH) conf_t = -1;
        if (ov < NEG_TH) conf_t = 0;
        bool pos = conf_t > 0;

        float conf0 = row[0];
        float lc = (pos || conf_t < 0) ? 0.0f : (logZ - conf0);
        int cls = pos ? conf_t : 0;
        float ce = logZ - row[cls];

        lossc[bp] = lc;
        ce_neg[bp] = (conf_t == 0) ? ce : 0.0f;

        if (pos) {
            float4 t = ((const float4*)gt_boxes)[b * O_ + ti];
            float4 pr = ((const float4*)priors)[p];
            float mcx = (t.x + t.z) * 0.5f;
            float mcy = (t.y + t.w) * 0.5f;
            float gx = (mcx - pr.x) / (0.1f * pr.z);
            float gy = (mcy - pr.y) / (0.1f * pr.w);
            float gw = logf((t.z - t.x) / pr.z) / 0.2f;
            float gh = logf((t.w - t.y) / pr.w) / 0.2f;
            float4 ld = ((const float4*)loc_data)[bp];
            float sc2 = sl1(ld.x - gx) + sl1(ld.y - gy) + sl1(ld.z - gw) + sl1(ld.w - gh);
            atomicAdd(&s_lB, sc2);
            atomicAdd(&s_ceP, ce);
            atomicAdd(&s_np, 1);
        }
    }
    __syncthreads();
    if (tid == 0 && s_np > 0) {
        atomicAdd(&accum[0], s_lB);
        atomicAdd(&accum[1], s_ceP);
        atomicAdd(&num_pos[b], s_np);
    }
}

// Per-batch 1024-bin histogram of fb>>21 (monotone since lossc >= 0).
__global__ __launch_bounds__(512) void
k_hist(const float* __restrict__ lossc, int* __restrict__ hist) {
    __shared__ int h[HBINS];
    int b = blockIdx.y;
    const float* lc = lossc + (size_t)b * P_;
    for (int i = threadIdx.x; i < HBINS; i += 512) h[i] = 0;
    __syncthreads();
    int start = blockIdx.x * CHUNK;
    for (int i = start + threadIdx.x; i < start + CHUNK; i += 512)
        atomicAdd(&h[__float_as_uint(lc[i]) >> 21], 1);
    __syncthreads();
    int* gh = hist + b * HBINS;
    for (int i = threadIdx.x; i < HBINS; i += 512)
        if (h[i]) atomicAdd(&gh[i], h[i]);
}

// One block per batch: pick threshold bin from the 1024-bin histogram, then
// refine over remaining 21 value bits with two LDS-histogram passes over P,
// then sum selected ce. Bins-above-T ce is summed ONCE (pass A); the final
// selection passes are gated to bin == T only (the R5 bug was re-adding
// bins > T there). Exact stable-argsort tie-break on fb==V via index radix.
__global__ __launch_bounds__(512) void
k_ohem(const float* __restrict__ lossc, const float* __restrict__ ce_neg,
       const int* __restrict__ hist, const int* __restrict__ num_pos,
       float* __restrict__ ce_sum) {
    const int b = blockIdx.x;
    const int tid = threadIdx.x;
    const float* lc = lossc + (size_t)b * P_;
    const float* cn = ce_neg + (size_t)b * P_;
    __shared__ int h[2048];
    __shared__ int wsum[8];
    __shared__ int s_bin, s_kk;
    __shared__ float red[512];

    int k = 3 * num_pos[b];
    if (k > P_ - 1) k = P_ - 1;
    if (k <= 0) { if (tid == 0) ce_sum[b] = 0.0f; return; }

    // round 0: threshold bin T among top-11-bit bins (global hist, coalesced)
    pick_top<2>(hist + b * HBINS, k, tid, &s_bin, &s_kk, wsum);
    const unsigned int T = (unsigned int)s_bin;
    int kk = s_kk;

    // pass A: sum ce for bins > T; histogram bits 20..10 of bin==T elements
    for (int i = tid; i < 2048; i += 512) h[i] = 0;
    __syncthreads();
    float sum = 0.0f;
    for (int i = tid; i < P_; i += 512) {
        unsigned int fb = __float_as_uint(lc[i]);
        unsigned int bin = fb >> 21;
        if (bin > T) sum += cn[i];
        else if (bin == T) atomicAdd(&h[(fb >> 10) & 2047], 1);
    }
    __syncthreads();
    pick_top<4>(h, kk, tid, &s_bin, &s_kk, wsum);
    const unsigned int pre21 = (T << 11) | (unsigned int)s_bin;
    kk = s_kk;

    // pass B: histogram bits 9..0 of elements matching top 22 bits
    for (int i = tid; i < 1024; i += 512) h[i] = 0;
    __syncthreads();
    for (int i = tid; i < P_; i += 512) {
        unsigned int fb = __float_as_uint(lc[i]);
        if ((fb >> 10) == pre21) atomicAdd(&h[fb & 1023], 1);
    }
    __syncthreads();
    pick_top<2>(h, kk, tid, &s_bin, &s_kk, wsum);
    const unsigned int V = (pre21 << 10) | (unsigned int)s_bin;
    const int ee = h[s_bin];          // multiplicity of exact value V
    kk = s_kk;

    if (kk == ee) {
        // boundary doesn't split ties: select bin==T elements with fb >= V
        for (int i = tid; i < P_; i += 512) {
            unsigned int fb = __float_as_uint(lc[i]);
            if ((fb >> 21) == T && fb >= V) sum += cn[i];
        }
    } else {
        // bin==T: select fb > V, plus the kk smallest-index elements with
        // fb == V (stable argsort(-loss_c): ties ordered by ascending index)
        for (int i = tid; i < 512; i += 512) h[i] = 0;
        __syncthreads();
        for (int i = tid; i < P_; i += 512)
            if (__float_as_uint(lc[i]) == V) atomicAdd(&h[i >> 6], 1);
        __syncthreads();
        pick_bot<1>(h, kk, tid, &s_bin, &s_kk, wsum);
        const int d6 = s_bin;
        kk = s_kk;
        h[tid] = 0;
        __syncthreads();
        for (int i = tid; i < P_; i += 512)
            if (__float_as_uint(lc[i]) == V && (i >> 6) == d6) atomicAdd(&h[i & 63], 1);
        __syncthreads();
        pick_bot<1>(h, kk, tid, &s_bin, &s_kk, wsum);
        const int Istar = (d6 << 6) | s_bin;
        for (int i = tid; i < P_; i += 512) {
            unsigned int fb = __float_as_uint(lc[i]);
            if ((fb >> 21) == T && (fb > V || (fb == V && i <= Istar))) sum += cn[i];
        }
    }

    red[tid] = sum;
    __syncthreads();
    for (int s = 256; s > 0; s >>= 1) {
        if (tid < s) red[tid] += red[tid + s];
        __syncthreads();
    }
    if (tid == 0) ce_sum[b] = red[0];
}

__global__ void k_final(const int* __restrict__ num_pos,
                        const float* __restrict__ ce_sum,
                        const float* __restrict__ accum,
                        float* __restrict__ out) {
    if (threadIdx.x != 0) return;
    int tp = 0; float ns = 0.0f;
    for (int b = 0; b < B_; ++b) { tp += num_pos[b]; ns += ce_sum[b]; }
    float inv = 1.0f / (float)tp;
    out[0] = accum[0] * 1.5f * inv;          // BBOX_ALPHA
    out[1] = (accum[1] + ns) * 1.0f * inv;   // CONF_ALPHA
}

extern "C" void kernel_launch(void* const* d_in, const int* in_sizes, int n_in,
                              void* d_out, int out_size, void* d_ws, size_t ws_size,
                              hipStream_t stream) {
    const float* loc    = (const float*)d_in[0];
    const float* conf   = (const float*)d_in[1];
    const float* priors = (const float*)d_in[2];
    const float* gtb    = (const float*)d_in[3];
    const int*   gtl    = (const int*)d_in[4];
    float* out = (float*)d_out;

    const size_t BP = (size_t)B_ * P_;
    float* W = (float*)d_ws;
    float* bt_ov    = W;
    int*   bt_ix    = (int*)(W + BP);
    float* lossc    = W + 2 * BP;
    float* ce_neg   = W + 3 * BP;
    int*   hist     = (int*)(W + 4 * BP);
    int*   best_pr  = hist + B_ * HBINS;
    int*   num_pos  = best_pr + B_ * O_;
    float* ce_sum   = (float*)(num_pos + B_);
    float* accum    = ce_sum + B_;

    hipLaunchKernelGGL(k_init, dim3(32), dim3(512), 0, stream,
                       hist, num_pos, accum);
    hipLaunchKernelGGL(k_best_prior, dim3(B_ * O_), dim3(256), 0, stream,
                       priors, gtb, best_pr);
    hipLaunchKernelGGL(k_best_truth, dim3((P_ + 255) / 256, B_), dim3(256), 0, stream,
                       priors, gtb, bt_ov, bt_ix);
    hipLaunchKernelGGL(k_force, dim3(1), dim3(64), 0, stream, best_pr, bt_ov, bt_ix);
    hipLaunchKernelGGL(k_main, dim3((int)(BP / RPB)), dim3(TPB), 0, stream,
                       loc, conf, priors, gtb, gtl, bt_ov, bt_ix,
                       lossc, ce_neg, num_pos, accum);
    hipLaunchKernelGGL(k_hist, dim3(8, B_), dim3(512), 0, stream, lossc, hist);
    hipLaunchKernelGGL(k_ohem, dim3(B_), dim3(512), 0, stream,
                       lossc, ce_neg, hist, num_pos, ce_sum);
    hipLaunchKernelGGL(k_final, dim3(1), dim3(64), 0, stream,
                       num_pos, ce_sum, accum, out);
}